// Round 2
// 11324.562 us; speedup vs baseline: 1.1584x; 1.1584x over previous
//
#include <hip/hip_runtime.h>
#include <math.h>

#define TT 19
#define TPREV 10

typedef __attribute__((ext_vector_type(8))) short bf8v;
typedef __attribute__((ext_vector_type(4))) float f4v;
typedef __attribute__((ext_vector_type(16))) float f16v;

__device__ __forceinline__ float sigmoidf_(float x){ return 1.f/(1.f+expf(-x)); }
__device__ __forceinline__ unsigned short f2bf(float x){
    unsigned int u = __float_as_uint(x);
    u += 0x7FFFu + ((u>>16)&1u);
    return (unsigned short)(u>>16);
}
__device__ __forceinline__ float bf2f(unsigned short b){ return __uint_as_float(((unsigned int)b)<<16); }

// RULE (R4, keep forever): NEVER use the offset-immediate arg of
// global_load_lds — it corrupts the LDS destination address. offset=0 +
// explicit pointer arithmetic only.
#define GLDS(g, l) __builtin_amdgcn_global_load_lds( \
    (const __attribute__((address_space(1))) void*)(g),   \
    (__attribute__((address_space(3))) void*)(l), 16, 0, 0)

// ------------------------------------------------------------------
// Halo-LDS implicit-GEMM conv, 32x32x16 MFMA core.
// Weight tiles: [oct(k/8)][row 0..127][8] bf16, 8KB each, linear stream,
// 1-tile-ahead GLDS prefetch (double buffer). Activations: halo in LDS,
// staged once per 32-ci chunk. cl==4 seg = l0 x-input gather path.
// A layout: lane holds row=lane&31, k=(lane>>5)*8+j  (32x32x16 bf16)
// C/D:      col=lane&31, row=(reg&3)+8*(reg>>2)+4*(lane>>5)
// ------------------------------------------------------------------
struct HSeg {
    const unsigned short* in;
    int cl;        // log2(Cin); 4 -> gather path
    int c0;        // absolute ci base
    int nch;       // number of 32-ci chunks
    int tap0, ntaps, five;
};
struct HJob {
    const unsigned short* wt;   // tile stream
    const unsigned short* w4;   // cl4 gather weights ([row][416]) or unused
    float* out;
    int cout_stride, pad;
    HSeg s;
};
struct HJobs14 { HJob j[14]; };
struct HJobs9  { HJob j[9]; };
struct HJobs7  { HJob j[7]; };

template<typename JOBS>
__global__ __launch_bounds__(256) void hconv_kernel(JOBS jobs, const unsigned short* zp)
{
    __shared__ unsigned short sA[8192];    // 2 x 8KB tile buffers
    __shared__ unsigned short sH[12800];   // halo 8x40 cells x stride40
    const HJob jb = jobs.j[blockIdx.y];
    const int tid = threadIdx.x;

    const int rA = tid & 127;
    const int q1 = tid >> 7;

    const int ng0 = blockIdx.x * 128;
    const int bb = ng0 >> 10, p0 = ng0 & 1023;
    const int y0 = p0 >> 5;

    const int lane = tid & 63, wv = tid >> 6;
    const int wm = (wv & 1) << 6;
    const int wn = (wv >> 1) << 6;
    const int col = lane & 31, ll5 = lane >> 5;

    // halo read bases per ni (tap-independent); oct base = ll5
    int bofs0[2];
#pragma unroll
    for (int ni = 0; ni < 2; ++ni) {
        const int ln = wn + ni * 32 + col;
        bofs0[ni] = (((ln >> 5) + 2) * 40 + (ln & 31) + 4) * 40 + ll5 * 8;
    }

    f16v acc[2][2];
#pragma unroll
    for (int i = 0; i < 2; ++i)
#pragma unroll
        for (int j = 0; j < 2; ++j) acc[i][j] = (f16v)0.f;

    const HSeg sg = jb.s;

    if (sg.cl == 4) {
        // ---- gather path (Cin=16, K=416, BK=32) ----
        const unsigned short* wrow4 = jb.w4 + (size_t)rA * 416 + q1 * 8;
        const unsigned short* inb4 = sg.in + ((size_t)bb << 14);
        const int pyy = y0 + (rA >> 5), pxx = rA & 31;
        for (int k = 0; k < 416; k += 32) {
            const unsigned short* gA = wrow4 + k;
            GLDS(gA,      &sA[tid * 8]);
            GLDS(gA + 16, &sA[(tid + 256) * 8]);
#pragma unroll
            for (int cc = 0; cc < 2; ++cc) {
                const int kk = k + q1 * 8 + cc * 16;
                const int tap = kk >> 4;
                const int ci = kk & 15;
                const int t5 = (tap * 52) >> 8;
                const int yy = pyy + t5 - 2;
                const int xx = pxx + (tap - t5 * 5) - 2;
                const bool ok = (tap < 25) & ((unsigned)yy < 32u) & ((unsigned)xx < 32u);
                const unsigned short* gp = ok ? (inb4 + ((((yy << 5) + xx)) << 4) + ci) : zp;
                GLDS(gp, cc ? &sH[(tid + 256) * 8] : &sH[tid * 8]);
            }
            __syncthreads();
#pragma unroll
            for (int s = 0; s < 2; ++s) {
                const int o = s * 2 + ll5;
                bf8v av[2], bv[2];
#pragma unroll
                for (int mi = 0; mi < 2; ++mi)
                    av[mi] = *(const bf8v*)&sA[(o * 128 + wm + mi * 32 + col) * 8];
#pragma unroll
                for (int ni = 0; ni < 2; ++ni)
                    bv[ni] = *(const bf8v*)&sH[(o * 128 + wn + ni * 32 + col) * 8];
#pragma unroll
                for (int mi = 0; mi < 2; ++mi)
#pragma unroll
                    for (int ni = 0; ni < 2; ++ni)
                        acc[mi][ni] = __builtin_amdgcn_mfma_f32_32x32x16_bf16(
                            av[mi], bv[ni], acc[mi][ni], 0, 0, 0);
            }
            __syncthreads();
        }
    } else {
        // ---- stream path ----
        const unsigned short* inb = sg.in + ((size_t)bb << (10 + sg.cl));
        const unsigned short* wptr = jb.wt;
        int buf = 0;
        bool first = true;
        for (int ch = 0; ch < sg.nch; ++ch) {
            const int c0 = sg.c0 + ch * 32;
            // stage halo: 1280 slots of 16B, 5 per thread
#pragma unroll
            for (int k = 0; k < 5; ++k) {
                const int s = tid + k * 256;
                const int r = s / 160;
                const int rem = s - r * 160;
                const int cc = rem >> 2, G = rem & 3;
                const int y = y0 + r - 2, x = cc - 4;
                const bool okv = ((unsigned)y < 32u) & ((unsigned)x < 32u);
                const int yc = okv ? y : 0, xc = okv ? x : 0;
                bf8v v = *(const bf8v*)(inb + ((((yc << 5) + xc)) << sg.cl) + c0 + G * 8);
                if (!okv) v = (bf8v)(short)0;
                *(bf8v*)&sH[(r * 40 + cc) * 40 + G * 8] = v;
            }
            if (first) {
                GLDS(wptr + tid * 8,         &sA[tid * 8]);
                GLDS(wptr + (tid + 256) * 8, &sA[(tid + 256) * 8]);
                wptr += 4096;
                first = false;
            }
            __syncthreads();
            for (int t = 0; t < sg.ntaps; ++t) {
                // prefetch next tile into buf^1
                GLDS(wptr + tid * 8,         &sA[(buf ^ 1) * 4096 + tid * 8]);
                GLDS(wptr + (tid + 256) * 8, &sA[(buf ^ 1) * 4096 + (tid + 256) * 8]);
                wptr += 4096;
                int tapofs = 0;
                if (sg.five) {
                    const int tap = sg.tap0 + t;
                    const int t5 = (tap * 52) >> 8;
                    tapofs = ((t5 - 2) * 40 + (tap - t5 * 5 - 2)) * 40;
                }
                const unsigned short* sAb = &sA[buf * 4096];
#pragma unroll
                for (int s = 0; s < 2; ++s) {
                    const int o = s * 2 + ll5;
                    bf8v av[2], bv[2];
#pragma unroll
                    for (int mi = 0; mi < 2; ++mi)
                        av[mi] = *(const bf8v*)&sAb[(o * 128 + wm + mi * 32 + col) * 8];
#pragma unroll
                    for (int ni = 0; ni < 2; ++ni)
                        bv[ni] = *(const bf8v*)&sH[bofs0[ni] + tapofs + s * 16];
#pragma unroll
                    for (int mi = 0; mi < 2; ++mi)
#pragma unroll
                        for (int ni = 0; ni < 2; ++ni)
                            acc[mi][ni] = __builtin_amdgcn_mfma_f32_32x32x16_bf16(
                                av[mi], bv[ni], acc[mi][ni], 0, 0, 0);
                }
                __syncthreads();
                buf ^= 1;
            }
        }
    }

    // epilogue (32x32 C/D): col=lane&31, row=(reg&3)+8*(reg>>2)+4*ll5
    const int nfix = ng0 + wn + col;
#pragma unroll
    for (int ni = 0; ni < 2; ++ni) {
        const int n = nfix + ni * 32;
        float* ob = jb.out + (size_t)n * jb.cout_stride;
#pragma unroll
        for (int mi = 0; mi < 2; ++mi) {
            const int mb = wm + mi * 32 + 4 * ll5;
            const f16v a = acc[mi][ni];
#pragma unroll
            for (int qd = 0; qd < 4; ++qd) {
                f4v v;
                v[0] = a[qd * 4 + 0]; v[1] = a[qd * 4 + 1];
                v[2] = a[qd * 4 + 2]; v[3] = a[qd * 4 + 3];
                *(f4v*)(ob + mb + qd * 8) = v;
            }
        }
    }
}

// ------------------------------------------------------------------
// hconvA: phase-A stream-path kernel, deep-pipelined (T2+T4+T5 combo).
//   N-tile 256 px (8 rows), M=128, 4 waves, wave tile 64x128 (2x4 of
//   32x32) -> 16 MFMA / 12 ds_read_b128 per tap per wave (0.75 rd/MFMA
//   vs 1.0 in hconv_kernel).
//   Weight pipeline: 4 x 8KB LDS buffers, GLDS issue at tap t targets
//   buf[(t+2)&3]; counted s_waitcnt vmcnt(4) (never 0 in steady state);
//   ONE s_barrier per tap.
//   Safety invariants (do not edit without re-deriving):
//   - buf[(t+2)&3] was last ds_read at tap t-2; those reads complete
//     before each wave's explicit lgkmcnt(0) preceding barrier A(t-1),
//     and the GLDS issue at t is after barrier A(t-1) in program order
//     for every wave -> no overwrite race with 1 barrier/tap.
//   - tile t completeness: own vmcnt(4) (outstanding = tiles t+1,t+2)
//     + barrier A(t) covers other waves' GLDS.
//   - sH restage happens only after a full __syncthreads() (drains,
//     costs a bubble 3x per job - acceptable).
//   sH G-slot XOR swizzle: cell stride 40 shorts (20 dw) makes lanes
//   {c,c+8,c+16,c+24} 4-way bank-alias; storing ci-group G at slot
//   G ^ ((cell>>3)&3) gives the 4 aliasing lanes 4 distinct 16B slots
//   -> conflict-free ds_read_b128. Swizzle applied on BOTH write (stage)
//   and read (baddr) sides.
// ------------------------------------------------------------------
template<typename JOBS>
__global__ __launch_bounds__(256, 2) void hconvA_kernel(JOBS jobs, const unsigned short* zp)
{
    __shared__ unsigned short sA[16384];   // 4 x 8KB weight tile buffers
    __shared__ unsigned short sH[19200];   // halo 12 rows x 40 cells x 40 shorts, swizzled
    const int tid = threadIdx.x;

    // XCD-clustered job mapping: bid%8 ~ XCD; give each XCD-class a
    // contiguous range of (job, xtile) so each XCD streams <=2 weight
    // streams (L2-resident) instead of all jobs. Requires nb%8==0 and
    // gridDim.x==32 (both true for all launches of this kernel).
    const int nb   = gridDim.x * gridDim.y;
    const int per8 = nb >> 3;
    const int bidl = blockIdx.x + gridDim.x * blockIdx.y;
    const int g    = (bidl & 7) * per8 + (bidl >> 3);
    const int jy   = g >> 5;
    const int xt   = g & 31;
    const HJob jb = jobs.j[jy];

    const int ng0 = xt << 8;
    const int bb = ng0 >> 10, p0 = ng0 & 1023;
    const int y0 = p0 >> 5;          // {0,8,16,24}

    const int lane = tid & 63, wv = tid >> 6;
    const int wm = (wv & 1) << 6;    // M base 0/64
    const int wn = (wv >> 1) << 7;   // N base 0/128
    const int col = lane & 31, ll5 = lane >> 5;

    // tap-independent halo cell index per ni (local halo coords)
    int cell0[4];
#pragma unroll
    for (int ni = 0; ni < 4; ++ni) {
        const int ln = wn + ni * 32 + col;
        cell0[ni] = ((ln >> 5) + 2) * 40 + (ln & 31) + 4;
    }
    const int rowA0 = (wm + col) * 8;    // A-tile: + mi*256 + s*2048 + ll5*1024
    const int oA = ll5 * 1024;

    f16v acc[2][4];
#pragma unroll
    for (int i = 0; i < 2; ++i)
#pragma unroll
        for (int j = 0; j < 4; ++j) acc[i][j] = (f16v)0.f;

    const HSeg sg = jb.s;
    const unsigned short* inb = sg.in + ((size_t)bb << (10 + sg.cl));
    const unsigned short* wptr = jb.wt;
    const int ntaps = sg.ntaps;
    const int ntot = sg.nch * ntaps;

    // ---- stage chunk 0 halo (1920 16B slots, swizzled) ----
    {
        const int c0 = sg.c0;
#pragma unroll
        for (int k = 0; k < 8; ++k) {
            const int s = tid + k * 256;
            if (s < 1920) {
                const int r = s / 160;
                const int rem = s - r * 160;
                const int cc = rem >> 2, G = rem & 3;
                const int y = y0 + r - 2, x = cc - 4;
                const bool okv = ((unsigned)y < 32u) & ((unsigned)x < 32u);
                const int yc = okv ? y : 0, xc = okv ? x : 0;
                bf8v v = *(const bf8v*)(inb + ((((yc << 5) + xc)) << sg.cl) + c0 + G * 8);
                if (!okv) v = (bf8v)(short)0;
                const int cell = r * 40 + cc;
                *(bf8v*)&sH[cell * 40 + ((G ^ ((cell >> 3) & 3))) * 8] = v;
            }
        }
    }
    // ---- prologue: issue tiles 0,1 into buf0,buf1 ----
    GLDS(wptr + tid * 8,                &sA[tid * 8]);
    GLDS(wptr + (tid + 256) * 8,        &sA[(tid + 256) * 8]);
    GLDS(wptr + 4096 + tid * 8,         &sA[4096 + tid * 8]);
    GLDS(wptr + 4096 + (tid + 256) * 8, &sA[4096 + (tid + 256) * 8]);
    wptr += 8192;

    int bcur = 0, tc = 0, ch = 0;
    for (int t = 0; t < ntot; ++t) {
        if (tc == ntaps) {
            tc = 0; ++ch;
            __syncthreads();   // all waves done reading sH (full drain, 3x/job)
            const int c0 = sg.c0 + ch * 32;
#pragma unroll
            for (int k = 0; k < 8; ++k) {
                const int s = tid + k * 256;
                if (s < 1920) {
                    const int r = s / 160;
                    const int rem = s - r * 160;
                    const int cc = rem >> 2, G = rem & 3;
                    const int y = y0 + r - 2, x = cc - 4;
                    const bool okv = ((unsigned)y < 32u) & ((unsigned)x < 32u);
                    const int yc = okv ? y : 0, xc = okv ? x : 0;
                    bf8v v = *(const bf8v*)(inb + ((((yc << 5) + xc)) << sg.cl) + c0 + G * 8);
                    if (!okv) v = (bf8v)(short)0;
                    const int cell = r * 40 + cc;
                    *(bf8v*)&sH[cell * 40 + ((G ^ ((cell >> 3) & 3))) * 8] = v;
                }
            }
        }
        // issue tile t+2 into buf[(bcur+2)&3]
        if (t + 2 < ntot) {
            const int b2 = (bcur + 2) & 3;
            GLDS(wptr + tid * 8,         &sA[b2 * 4096 + tid * 8]);
            GLDS(wptr + (tid + 256) * 8, &sA[b2 * 4096 + (tid + 256) * 8]);
            wptr += 4096;
        }
        // swizzled B addresses for this tap
        int tapofs = 0;
        if (sg.five) {
            const int tap = sg.tap0 + tc;
            const int t5 = (tap * 52) >> 8;
            tapofs = (t5 - 2) * 40 + (tap - t5 * 5 - 2);
        }
        int baddr[4][2];
#pragma unroll
        for (int ni = 0; ni < 4; ++ni) {
            const int cT = cell0[ni] + tapofs;
            const int key = (cT >> 3) & 3;
            const int cb = cT * 40;
#pragma unroll
            for (int s = 0; s < 2; ++s)
                baddr[ni][s] = cb + (((s << 1) + ll5) ^ key) * 8;
        }
        // counted waits: own tile-t loads (oldest) done; lgkmcnt(0) makes
        // own ds_writes (stage taps) visible before the barrier.
        if (t + 2 < ntot)      asm volatile("s_waitcnt vmcnt(4) lgkmcnt(0)" ::: "memory");
        else if (t + 1 < ntot) asm volatile("s_waitcnt vmcnt(2) lgkmcnt(0)" ::: "memory");
        else                   asm volatile("s_waitcnt vmcnt(0) lgkmcnt(0)" ::: "memory");
        __builtin_amdgcn_s_barrier();          // barrier A(t)
        __builtin_amdgcn_sched_barrier(0);

        const unsigned short* sAb = &sA[bcur * 4096];
        bf8v av[2][2], bv[2][4];
#pragma unroll
        for (int s = 0; s < 2; ++s) {
#pragma unroll
            for (int mi = 0; mi < 2; ++mi)
                av[s][mi] = *(const bf8v*)&sAb[s * 2048 + oA + rowA0 + mi * 256];
#pragma unroll
            for (int ni = 0; ni < 4; ++ni)
                bv[s][ni] = *(const bf8v*)&sH[baddr[ni][s]];
        }
        __builtin_amdgcn_s_setprio(1);
#pragma unroll
        for (int s = 0; s < 2; ++s)
#pragma unroll
            for (int mi = 0; mi < 2; ++mi)
#pragma unroll
                for (int ni = 0; ni < 4; ++ni)
                    acc[mi][ni] = __builtin_amdgcn_mfma_f32_32x32x16_bf16(
                        av[s][mi], bv[s][ni], acc[mi][ni], 0, 0, 0);
        __builtin_amdgcn_s_setprio(0);
        __builtin_amdgcn_sched_barrier(0);

        bcur = (bcur + 1) & 3;
        ++tc;
    }

    // epilogue (32x32 C/D): col=lane&31, row=(reg&3)+8*(reg>>2)+4*ll5
    const int nfix = ng0 + wn + col;
#pragma unroll
    for (int ni = 0; ni < 4; ++ni) {
        const int n = nfix + ni * 32;
        float* ob = jb.out + (size_t)n * jb.cout_stride;
#pragma unroll
        for (int mi = 0; mi < 2; ++mi) {
            const int mb = wm + mi * 32 + 4 * ll5;
            const f16v a = acc[mi][ni];
#pragma unroll
            for (int qd = 0; qd < 4; ++qd) {
                f4v v;
                v[0] = a[qd * 4 + 0]; v[1] = a[qd * 4 + 1];
                v[2] = a[qd * 4 + 2]; v[3] = a[qd * 4 + 3];
                *(f4v*)(ob + mb + qd * 8) = v;
            }
        }
    }
}

// ------------------------------------------------------------------
// packT: OIHW f32 -> linear tile stream [at][oct][row][8] bf16
// ------------------------------------------------------------------
__global__ __launch_bounds__(256) void packT_kernel(
    const float* __restrict__ src, unsigned short* __restrict__ dst,
    int Cin, int srcTaps, int rowOff, int ci0, int ntaps, int tap0, int total)
{
    const int idx = blockIdx.x * 256 + threadIdx.x;
    if (idx >= total) return;
    const int j = idx & 7;
    const int row = (idx >> 3) & 127;
    const int q = (idx >> 10) & 3;
    const int at = idx >> 12;
    const int ch = at / ntaps;
    const int tap = tap0 + (at - ch * ntaps);
    const int ci = ci0 + ch * 32 + q * 8 + j;
    const float v = src[((size_t)(rowOff + row) * Cin + ci) * srcTaps + tap];
    dst[idx] = f2bf(v);
}

__global__ __launch_bounds__(256) void pack4_kernel(
    const float* __restrict__ src, unsigned short* __restrict__ dst, int total)
{
    const int idx = blockIdx.x * 256 + threadIdx.x;
    if (idx >= total) return;
    const int ci = idx & 15;
    const int t2 = idx >> 4;
    const int tap = t2 % 26;
    const int co = t2 / 26;
    float v = 0.f;
    if (tap < 25)
        v = src[((size_t)(co << 4) + ci) * 25 + tap];
    dst[idx] = f2bf(v);
}

__global__ __launch_bounds__(256) void net_kernel(
    const float* __restrict__ frames, const float* __restrict__ mask,
    const float* __restrict__ xgen, unsigned short* __restrict__ net, int t)
{
    const int idx = blockIdx.x * 256 + threadIdx.x;  // 8192*16
    const int n = idx >> 4, ch = idx & 15;
    const int b = n >> 10, p = n & 1023;
    const float fr = frames[((((size_t)b * 20 + t) << 10) + p) * 16 + ch];
    float v;
    if (t < TPREV) v = fr;
    else {
        const float mk = mask[((((size_t)b * 9 + (t - TPREV)) << 10) + p) * 16 + ch];
        v = mk * fr + (1.f - mk) * xgen[idx];
    }
    net[idx] = f2bf(v);
}

__global__ __launch_bounds__(256) void gates_kernel(
    const float* __restrict__ preA, const float* __restrict__ preB,
    float* __restrict__ c, float* __restrict__ m,
    unsigned short* __restrict__ m_bf, unsigned short* __restrict__ mem)
{
    const int idx = blockIdx.x * 256 + threadIdx.x;  // 8192*128
    const int n = idx >> 7, ch = idx & 127;
    const float* pa = preA + (size_t)n * 896 + ch;
    const float* pb = preB + (size_t)n * 896 + ch;
    const float i_ = pa[0]   + pb[0];
    const float f_ = pa[128] + pb[128];
    const float g_ = pa[256] + pb[256];
    const float ip = pa[384] + pb[384];
    const float fp = pa[512] + pb[512];
    const float gp = pa[640] + pb[640];
    const float cn = sigmoidf_(f_ + 1.f) * c[idx] + sigmoidf_(i_) * tanhf(g_);
    const float mn = sigmoidf_(fp + 1.f) * m[idx] + sigmoidf_(ip) * tanhf(gp);
    c[idx] = cn;
    m[idx] = mn;
    m_bf[idx] = f2bf(mn);
    mem[(size_t)n * 256 + ch] = f2bf(cn);
    mem[(size_t)n * 256 + 128 + ch] = f2bf(mn);
}

__global__ __launch_bounds__(256) void hout_kernel(
    const float* __restrict__ preA, const float* __restrict__ preB,
    const float* __restrict__ opart, const float* __restrict__ lconv,
    unsigned short* __restrict__ h)
{
    const int idx = blockIdx.x * 256 + threadIdx.x;  // 8192*128
    const int n = idx >> 7, ch = idx & 127;
    float oc = preA[(size_t)n * 896 + 768 + ch] + preB[(size_t)n * 896 + 768 + ch];
#pragma unroll
    for (int j = 0; j < 8; ++j) oc += opart[idx + (size_t)j * 1048576];
    h[idx] = f2bf(sigmoidf_(oc) * tanhf(lconv[idx]));
}

__global__ __launch_bounds__(256) void wout_kernel(
    const unsigned short* __restrict__ h3, const float* __restrict__ wo,
    float* __restrict__ xgen, float* __restrict__ out, int t)
{
    const int idx = blockIdx.x * 256 + threadIdx.x;  // 8192*16
    const int n = idx >> 4, ch = idx & 15;
    const int b = n >> 10, p = n & 1023;
    const unsigned short* hr = h3 + (size_t)n * 128;
    const float* wr = wo + ch * 128;
    float acc = 0.f;
#pragma unroll 8
    for (int ci = 0; ci < 128; ++ci)
        acc = fmaf(bf2f(hr[ci]), wr[ci], acc);
    xgen[idx] = acc;
    out[((((size_t)b * TT + t) << 10) + p) * 16 + ch] = acc;
}

extern "C" void kernel_launch(void* const* d_in, const int* in_sizes, int n_in,
                              void* d_out, int out_size, void* d_ws, size_t ws_size,
                              hipStream_t stream)
{
    const float* frames = (const float*)d_in[0];
    const float* mask   = (const float*)d_in[1];
    const float* Wx0    = (const float*)d_in[2];
    const float* Wx     = (const float*)d_in[3];
    const float* Wh     = (const float*)d_in[4];
    const float* Wm     = (const float*)d_in[5];
    const float* Wo     = (const float*)d_in[6];
    const float* Wl     = (const float*)d_in[7];
    const float* Wout   = (const float*)d_in[8];
    float* out = (float*)d_out;

    char* base = (char*)d_ws;
    size_t off = 0;
    auto take = [&](size_t bytes) -> char* {
        char* p = base + off;
        off = (off + bytes + 255) & ~(size_t)255;
        return p;
    };
    // ---- zero-init region ----
    float* c0            = (float*)take(4ull * 1048576 * 4);
    float* m32           = (float*)take((size_t)1048576 * 4);
    unsigned short* hbf  = (unsigned short*)take(4ull * 1048576 * 2);
    unsigned short* mbf  = (unsigned short*)take((size_t)1048576 * 2);
    unsigned short* zp   = (unsigned short*)take(1024);
    const size_t zbytes = off;
    // ---- working buffers ----
    float* xgen          = (float*)take((size_t)131072 * 4);
    float* preA          = (float*)take((size_t)8192 * 896 * 4);
    float* preB          = (float*)take((size_t)8192 * 896 * 4);
    float* lconv         = (float*)take((size_t)1048576 * 4);
    float* opart         = (float*)take(8ull * 1048576 * 4);
    unsigned short* net  = (unsigned short*)take((size_t)131072 * 2);
    unsigned short* mem  = (unsigned short*)take((size_t)2097152 * 2);
    // ---- packed weights (tile streams; +4096 el pad for prefetch overrun) ----
    unsigned short* pa0x = (unsigned short*)take((size_t)896 * 416 * 2);
    unsigned short* paT0 = (unsigned short*)take(((size_t)7 * 100 * 4096 + 4096) * 2);
    unsigned short* paT1 = (unsigned short*)take(((size_t)7 * 200 * 4096 + 4096) * 2);
    unsigned short* paT2 = (unsigned short*)take(((size_t)7 * 200 * 4096 + 4096) * 2);
    unsigned short* paT3 = (unsigned short*)take(((size_t)7 * 200 * 4096 + 4096) * 2);
    unsigned short* paT[4] = { paT0, paT1, paT2, paT3 };
    unsigned short* oT   = (unsigned short*)take((4ull * 200 * 4096 + 4096) * 2);
    unsigned short* lT   = (unsigned short*)take((4ull * 8 * 4096 + 4096) * 2);

    hipMemsetAsync(d_ws, 0, zbytes, stream);

    auto packT = [&](const float* s, unsigned short* d, int Cin, int srcTaps,
                     int rowOff, int ci0, int nch, int ntaps, int tap0) {
        const int total = nch * ntaps * 4096;
        packT_kernel<<<(total + 255) / 256, 256, 0, stream>>>(
            s, d, Cin, srcTaps, rowOff, ci0, ntaps, tap0, total);
    };
    pack4_kernel<<<(896 * 416 + 255) / 256, 256, 0, stream>>>(Wx0, pa0x, 896 * 416);
    for (int g = 0; g < 7; ++g) {
        const float* hm0 = (g < 3) ? (Wh + (size_t)g * 128 * 128 * 25)
                         : (g == 6) ? (Wh + (size_t)384 * 128 * 25)
                                    : (Wm + (size_t)(g - 3) * 128 * 128 * 25);
        packT(hm0, paT0 + (size_t)g * 100 * 4096, 128, 25, 0, 0, 4, 25, 0);
        for (int l = 1; l < 4; ++l) {
            packT(Wx + (size_t)(l - 1) * 896 * 128 * 25,
                  paT[l] + (size_t)g * 200 * 4096, 128, 25, g * 128, 0, 4, 25, 0);
            const float* hmsrc = (g < 3) ? (Wh + ((size_t)l * 512 + g * 128) * 128 * 25)
                               : (g == 6) ? (Wh + ((size_t)l * 512 + 384) * 128 * 25)
                                          : (Wm + ((size_t)l * 384 + (g - 3) * 128) * 128 * 25);
            packT(hmsrc, paT[l] + ((size_t)g * 200 + 100) * 4096, 128, 25, 0, 0, 4, 25, 0);
        }
    }
    for (int l = 0; l < 4; ++l) {
        packT(Wo + (size_t)l * 128 * 256 * 25, oT + (size_t)l * 200 * 4096,
              256, 25, 0, 0, 8, 25, 0);
        packT(Wl + (size_t)l * 128 * 256, lT + (size_t)l * 8 * 4096,
              256, 1, 0, 0, 8, 1, 0);
    }

    for (int t = 0; t < TT; ++t) {
        net_kernel<<<512, 256, 0, stream>>>(frames, mask, xgen, net, t);
        for (int l = 0; l < 4; ++l) {
            unsigned short* hl = hbf + (size_t)l * 1048576;
            // ---- phase A ----
            if (l == 0) {
                // x-path: cl4 gather jobs on the classic kernel
                HJobs7 JG{}, JH{};
                for (int g = 0; g < 7; ++g) {
                    JG.j[g] = HJob{ pa0x, pa0x + (size_t)g * 128 * 416, preA + g * 128,
                                    896, 0, HSeg{ net, 4, 0, 0, 0, 0, 1 } };
                    const unsigned short* hmsrc = (g < 3 || g == 6) ? hl : mbf;
                    JH.j[g] = HJob{ paT0 + (size_t)g * 100 * 4096, nullptr, preB + g * 128,
                                    896, 0, HSeg{ hmsrc, 7, 0, 4, 0, 25, 1 } };
                }
                hconv_kernel<HJobs7><<<dim3(64, 7), 256, 0, stream>>>(JG, zp);
                hconvA_kernel<HJobs7><<<dim3(32, 7), 256, 0, stream>>>(JH, zp);
            } else {
                HJobs14 JA{};
                for (int g = 0; g < 7; ++g) {
                    const unsigned short* hmsrc = (g < 3 || g == 6) ? hl : mbf;
                    JA.j[g] = HJob{ paT[l] + (size_t)g * 200 * 4096, nullptr, preA + g * 128,
                                    896, 0, HSeg{ hbf + (size_t)(l - 1) * 1048576, 7, 0, 4, 0, 25, 1 } };
                    JA.j[7 + g] = HJob{ paT[l] + ((size_t)g * 200 + 100) * 4096, nullptr, preB + g * 128,
                                        896, 0, HSeg{ hmsrc, 7, 0, 4, 0, 25, 1 } };
                }
                hconvA_kernel<HJobs14><<<dim3(32, 14), 256, 0, stream>>>(JA, zp);
            }

            gates_kernel<<<4096, 256, 0, stream>>>(preA, preB,
                c0 + (size_t)l * 1048576, m32, mbf, mem);

            // ---- phase B: o-conv split by ci-chunk x8 + lconv (classic kernel)
            HJobs9 JB{};
            for (int jj = 0; jj < 8; ++jj)
                JB.j[jj] = HJob{ oT + ((size_t)l * 200 + jj * 25) * 4096, nullptr,
                                 opart + (size_t)jj * 1048576, 128, 0,
                                 HSeg{ mem, 8, jj * 32, 1, 0, 25, 1 } };
            JB.j[8] = HJob{ lT + (size_t)l * 8 * 4096, nullptr, lconv, 128, 0,
                            HSeg{ mem, 8, 0, 8, 0, 1, 0 } };
            hconv_kernel<HJobs9><<<dim3(64, 9), 256, 0, stream>>>(JB, zp);

            hout_kernel<<<4096, 256, 0, stream>>>(preA, preB, opart, lconv, hl);
        }
        wout_kernel<<<512, 256, 0, stream>>>(hbf + (size_t)3 * 1048576, Wout, xgen, out, t);
    }
}